// Round 10
// baseline (149.489 us; speedup 1.0000x reference)
//
#include <hip/hip_runtime.h>

#define BB 8
#define NN 1024
#define CC 128
#define GG 4
#define LL 8
#define GD 64

typedef __attribute__((ext_vector_type(8))) short short8;
typedef __attribute__((ext_vector_type(4))) short short4v;
typedef __attribute__((ext_vector_type(4))) float floatx4;

__device__ __forceinline__ short f2b(float f) {
  union { float f; unsigned u; } c; c.f = f;
  unsigned u = c.u;
  return (short)((u + 0x7FFFu + ((u >> 16) & 1u)) >> 16);   // RNE fp32->bf16
}
__device__ __forceinline__ float b2f(short s) {
  union { unsigned u; float f; } c; c.u = ((unsigned)(unsigned short)s) << 16;
  return c.f;
}
__device__ __forceinline__ void split2(float v, short& hi, short& lo) {
  short h = f2b(v);
  hi = h;
  lo = f2b(v - b2f(h));
}

// packed fp32x2 -> bf16x2 (dword: low=a, high=b)
#if __has_builtin(__builtin_amdgcn_cvt_pk_bf16_f32)
__device__ __forceinline__ unsigned pk2(float a, float b) {
  auto r = __builtin_amdgcn_cvt_pk_bf16_f32(a, b);
  unsigned u; __builtin_memcpy(&u, &r, 4); return u;
}
#else
__device__ __forceinline__ unsigned pk2(float a, float b) {
  return (unsigned)(unsigned short)f2b(a) | ((unsigned)(unsigned short)f2b(b) << 16);
}
#endif

#if __has_builtin(__builtin_amdgcn_exp2f)
#define EXP2(x) __builtin_amdgcn_exp2f(x)
#else
#define EXP2(x) exp2f(x)
#endif

// async global->LDS, 16B per lane, dest = base + lane*16 (linear)
#if __has_builtin(__builtin_amdgcn_global_load_lds)
__device__ __forceinline__ void gll16(const void* g, void* l, int lane) {
  (void)lane;
  __builtin_amdgcn_global_load_lds(
      (const __attribute__((address_space(1))) unsigned int*)g,
      (__attribute__((address_space(3))) unsigned int*)l, 16, 0, 0);
}
#else
__device__ __forceinline__ void gll16(const void* g, void* l, int lane) {
  uint4 t = *(const uint4*)g;
  *(uint4*)((char*)l + lane * 16) = t;
}
#endif

// ---------------- Kernel A: projections, W hi/lo-split staged in LDS ------
#define BHP 136   // shorts per W row in LDS; 68 dwords, 68%32=4 -> 2-way free

__global__ __launch_bounds__(256) void proj_kernel(
    const float* __restrict__ x, const float* __restrict__ Wq,
    const float* __restrict__ Wk, const float* __restrict__ Wv,
    short* __restrict__ qb, short* __restrict__ kb, short* __restrict__ vtb)
{
  __shared__ short bh[64 * BHP];   // 17408 B
  __shared__ short bl[64 * BHP];   // 17408 B
  const int t = threadIdx.x;
  const int nt = blockIdx.x & 3;
  const int mt = blockIdx.x >> 2;
  const int w = t >> 6;
  const int lane = t & 63;
  const int ln = lane & 15;
  const int hq = lane >> 4;
  const int arow = mt * 64 + w * 16 + ln;

  const float* wbase = (nt == 0) ? Wq : (nt == 1) ? Wk : (Wv + (nt - 2) * 64 * 128);

  // stage + split W: thread -> row t>>2, cols (t&3)*32..+31
  {
    int r = t >> 2, c0 = (t & 3) * 32;
    const float* src = wbase + r * 128 + c0;
    #pragma unroll
    for (int z8 = 0; z8 < 4; ++z8) {
      float4 u0 = *(const float4*)(src + z8 * 8);
      float4 u1 = *(const float4*)(src + z8 * 8 + 4);
      float uv[8] = {u0.x,u0.y,u0.z,u0.w,u1.x,u1.y,u1.z,u1.w};
      union { short s[8]; short8 v; } H, L;
      #pragma unroll
      for (int z = 0; z < 8; ++z) split2(uv[z], H.s[z], L.s[z]);
      *(short8*)(bh + r * BHP + c0 + z8 * 8) = H.v;
      *(short8*)(bl + r * BHP + c0 + z8 * 8) = L.v;
    }
  }
  __syncthreads();

  const floatx4 zf = {0.f, 0.f, 0.f, 0.f};
  floatx4 acc[4] = {zf, zf, zf, zf};

  #pragma unroll
  for (int kc = 0; kc < 4; ++kc) {
    const float* xp = x + (long)arow * 128 + kc * 32 + hq * 8;
    float4 a0 = *(const float4*)xp;
    float4 a1 = *(const float4*)(xp + 4);
    union { short s[8]; short8 v; } Ah, Al;
    float av[8] = {a0.x,a0.y,a0.z,a0.w,a1.x,a1.y,a1.z,a1.w};
    #pragma unroll
    for (int z = 0; z < 8; ++z) split2(av[z], Ah.s[z], Al.s[z]);
    #pragma unroll
    for (int ns = 0; ns < 4; ++ns) {
      short8 Bh = *(const short8*)(bh + (ns * 16 + ln) * BHP + kc * 32 + hq * 8);
      short8 Bl = *(const short8*)(bl + (ns * 16 + ln) * BHP + kc * 32 + hq * 8);
      acc[ns] = __builtin_amdgcn_mfma_f32_16x16x32_bf16(Ah.v, Bh, acc[ns], 0,0,0);
      acc[ns] = __builtin_amdgcn_mfma_f32_16x16x32_bf16(Al.v, Bh, acc[ns], 0,0,0);
      acc[ns] = __builtin_amdgcn_mfma_f32_16x16x32_bf16(Ah.v, Bl, acc[ns], 0,0,0);
    }
  }

  if (nt < 2) {
    short* dst = (nt == 0) ? qb : kb;
    #pragma unroll
    for (int ns = 0; ns < 4; ++ns) {
      int col = ns * 16 + ln;
      #pragma unroll
      for (int reg = 0; reg < 4; ++reg) {
        int row = mt * 64 + w * 16 + hq * 4 + reg;
        dst[(long)row * 64 + col] = f2b(acc[ns][reg]);
      }
    }
  } else {
    int b = mt >> 4;
    int tok = (mt * 64 + w * 16 + hq * 4) & 1023;
    #pragma unroll
    for (int ns = 0; ns < 4; ++ns) {
      int cv = (nt - 2) * 64 + ns * 16 + ln;
      union { short s[4]; short4v v; } o;
      #pragma unroll
      for (int reg = 0; reg < 4; ++reg) o.s[reg] = f2b(acc[ns][reg]);
      *(short4v*)(vtb + ((long)b * CC + cv) * NN + tok) = o.v;
    }
  }
}

// ---------------- Kernel B: swapped-QK (b128 arec writes) + K gll-prefetch -
// grid 1024 (= 4 blocks/CU co-resident at 37376 B LDS):
// sp = bx&1, itile = (bx>>1)&63, b = bx>>7.
// Per 64-j tile: barA (drains K-gll) | stage masks + QK<-kbuf | barB |
// issue gll(K of jt+1) | mix+PV.
// QK uses SWAPPED operands mfma(K, Q): D[row=j][col=i], so each lane's 4
// regs are 4 consecutive j for (i=ln, g=w) -> ONE b128 store per jsub into
// g-major arec[i][g*64+j] (16 b32 4x-conflicted stores -> 4 b128 min-phase).
// Mix reads arec per-g j-quads (b128, same count/phases as before).
#define IT 16
#define JT 64
#define SPLIT 2
#define JSPAN 512
#define NTL 8
#define ARP 260   // dwords per i-row of arec: arec[i][g*64 + j]  (g-major)
#define MRP 196   // dwords per i-row of mrec: mrec[i][j*3+m]

__global__ __launch_bounds__(256, 3) void attn_kernel(
    const short* __restrict__ qb, const short* __restrict__ kb,
    const short* __restrict__ vtb, const float* __restrict__ masks,
    const float* __restrict__ mask_proj,
    float* __restrict__ pnum, float* __restrict__ pden)
{
  __shared__ float arec[IT * ARP];   // 16640 B
  __shared__ float mrec[IT * MRP];   // 12544 B
  __shared__ short kbuf[64 * 64];    //  8192 B   (37376 B total)

  const int t = threadIdx.x;
  const int sp = blockIdx.x & 1;
  const int itile = (blockIdx.x >> 1) & 63;
  const int b = blockIdx.x >> 7;
  const int i0 = itile * IT;

  const int w = t >> 6;          // wave id: g (QK) ; l-pair owner (mix+PV)
  const int lane = t & 63;
  const int ln = lane & 15;
  const int hq = lane >> 4;
  const int l0 = 2 * w, l1 = 2 * w + 1;

  // Q B-fragment now (cols = i), K-dim zero-padded 16->32 (hq>=2 lanes zero)
  short8 qf;
  {
    union { short s[8]; short8 v; } qq;
    #pragma unroll
    for (int z = 0; z < 8; ++z) qq.s[z] = 0;
    if (hq < 2)
      qq.v = *(const short8*)(qb + ((long)(b * NN + i0 + ln)) * GD + w * 16 + hq * 8);
    qf = qq.v;
  }
  // mix constants folded into exp2 domain
  const float LOG2E = 1.44269504088896340736f;
  float ycA[3][4], ycB[3][4];
  #pragma unroll
  for (int m = 0; m < 3; ++m)
    #pragma unroll
    for (int g = 0; g < 4; ++g) {
      ycA[m][g] = mask_proj[m * 32 + g * 8 + l0] * LOG2E;
      ycB[m][g] = mask_proj[m * 32 + g * 8 + l1] * LOG2E;
    }

  const floatx4 zf = {0.f, 0.f, 0.f, 0.f};
  floatx4 pv0 = zf, pv1 = zf;
  float den0 = 0.f, den1 = 0.f;

  const short* kbase = kb + (long)b * NN * GD;
  const short* v0base = vtb + ((long)b * CC + l0 * 16 + ln) * NN;
  const short* v1base = vtb + ((long)b * CC + l1 * 16 + ln) * NN;

  // K-prefetch per-lane constants: wave w stages row-groups I = w*2, w*2+1
  const int klj = lane >> 3;              // row within 8-row group
  const int ke8 = (lane & 7) ^ klj;       // source d-octet (XOR pre-swizzle)

  // prologue: prefetch tile 0's K into kbuf (drained by first barA)
  #pragma unroll
  for (int ii = 0; ii < 2; ++ii) {
    const int I = w * 2 + ii;
    gll16(kbase + (long)(sp * JSPAN + I * 8 + klj) * GD + ke8 * 8,
          kbuf + I * 512, lane);
  }

  for (int jt = 0; jt < NTL; ++jt) {
    const int j0 = sp * JSPAN + jt * JT;
    __syncthreads();   // barA: prev mix readers done + K-gll drained (vmcnt 0)

    // ---- stage masks 16i x 64j x 3 (768 float4, coalesced) ----
    #pragma unroll
    for (int it2 = 0; it2 < 3; ++it2) {
      int f = t + it2 * 256;
      int ii = f / 48;
      int rem = f - ii * 48;
      *(float4*)(mrec + ii * MRP + rem * 4) =
        *(const float4*)(masks + (long)(i0 + ii) * (NN * 3) + (long)j0 * 3 + rem * 4);
    }
    // ---- QK swapped: at = mfma(K, Q) -> D[j][i]; b128 store per jsub ----
    #pragma unroll
    for (int jsub = 0; jsub < 4; ++jsub) {
      union { short s[8]; short8 v; } kk;
      #pragma unroll
      for (int z = 0; z < 8; ++z) kk.s[z] = 0;
      if (hq < 2) {
        const int jloc = jsub * 16 + ln;
        kk.v = *(const short8*)(kbuf + jloc * 64 + (((w * 2 + hq) ^ (jloc & 7)) << 3));
      }
      floatx4 at = __builtin_amdgcn_mfma_f32_16x16x32_bf16(kk.v, qf, zf, 0, 0, 0);
      // lane (ln,hq): rows hq*4+reg = j-local jsub*16+hq*4..+3, col ln = i
      *(floatx4*)(arec + ln * ARP + w * 64 + jsub * 16 + hq * 4) = at;
    }
    __syncthreads();   // barB: mrec + arec ready; all kbuf reads done

    // ---- issue NEXT tile's K prefetch (lands under the mix phase) ----
    {
      const int jn = sp * JSPAN + ((jt + 1) & (NTL - 1)) * JT;
      #pragma unroll
      for (int ii = 0; ii < 2; ++ii) {
        const int I = w * 2 + ii;
        gll16(kbase + (long)(jn + I * 8 + klj) * GD + ke8 * 8,
              kbuf + I * 512, lane);
      }
    }

    // ---- mix + exp2 + PV: thread = (i=ln, j-octet=hq), l = 2w, 2w+1 ----
    #pragma unroll
    for (int mf = 0; mf < 2; ++mf) {
      float mku[24];
      {
        const float* mb = mrec + ln * MRP + mf * 96 + hq * 24;
        #pragma unroll
        for (int q4 = 0; q4 < 6; ++q4)
          *(float4*)(mku + q4 * 4) = *(const float4*)(mb + q4 * 4);
      }
      short8 vf0 = *(const short8*)(v0base + j0 + mf * 32 + hq * 8);
      short8 vf1 = *(const short8*)(v1base + j0 + mf * 32 + hq * 8);
      const float* arA = arec + ln * ARP + mf * 32 + hq * 8;   // + g*64 + j
      union { unsigned u[4]; short8 v; } p0, p1;
      #pragma unroll
      for (int q = 0; q < 2; ++q) {
        // per-g j-quads (b128), g-major arec
        floatx4 ag0 = *(const floatx4*)(arA + 0 * 64 + q * 4);
        floatx4 ag1 = *(const floatx4*)(arA + 1 * 64 + q * 4);
        floatx4 ag2 = *(const floatx4*)(arA + 2 * 64 + q * 4);
        floatx4 ag3 = *(const floatx4*)(arA + 3 * 64 + q * 4);
        float eA[4], eB[4];
        #pragma unroll
        for (int zz = 0; zz < 4; ++zz) {
          int z = q * 4 + zz;
          float m0 = mku[z * 3], m1 = mku[z * 3 + 1], m2 = mku[z * 3 + 2];
          float wA0 = m0*ycA[0][0] + m1*ycA[1][0] + m2*ycA[2][0];
          float wA1 = m0*ycA[0][1] + m1*ycA[1][1] + m2*ycA[2][1];
          float wA2 = m0*ycA[0][2] + m1*ycA[1][2] + m2*ycA[2][2];
          float wA3 = m0*ycA[0][3] + m1*ycA[1][3] + m2*ycA[2][3];
          float wB0 = m0*ycB[0][0] + m1*ycB[1][0] + m2*ycB[2][0];
          float wB1 = m0*ycB[0][1] + m1*ycB[1][1] + m2*ycB[2][1];
          float wB2 = m0*ycB[0][2] + m1*ycB[1][2] + m2*ycB[2][2];
          float wB3 = m0*ycB[0][3] + m1*ycB[1][3] + m2*ycB[2][3];
          float sA = ag0[zz]*wA0 + ag1[zz]*wA1 + ag2[zz]*wA2 + ag3[zz]*wA3;
          float sB = ag0[zz]*wB0 + ag1[zz]*wB1 + ag2[zz]*wB2 + ag3[zz]*wB3;
          eA[zz] = EXP2(sA);
          eB[zz] = EXP2(sB);
        }
        den0 += eA[0] + eA[1] + eA[2] + eA[3];
        den1 += eB[0] + eB[1] + eB[2] + eB[3];
        p0.u[q * 2 + 0] = pk2(eA[0], eA[1]);
        p0.u[q * 2 + 1] = pk2(eA[2], eA[3]);
        p1.u[q * 2 + 0] = pk2(eB[0], eB[1]);
        p1.u[q * 2 + 1] = pk2(eB[2], eB[3]);
      }
      pv0 = __builtin_amdgcn_mfma_f32_16x16x32_bf16(p0.v, vf0, pv0, 0, 0, 0);
      pv1 = __builtin_amdgcn_mfma_f32_16x16x32_bf16(p1.v, vf1, pv1, 0, 0, 0);
    }
  }

  // ---- epilogue: partial numerators; den reduced over hq via shuffles ----
  #pragma unroll
  for (int reg = 0; reg < 4; ++reg) {
    long row = ((long)(sp * BB + b)) * NN + i0 + hq * 4 + reg;
    pnum[row * CC + l0 * 16 + ln] = pv0[reg];
    pnum[row * CC + l1 * 16 + ln] = pv1[reg];
  }
  // sum den over the 4 hq lanes (stride-16 within the wave)
  den0 += __shfl_xor(den0, 16, 64);
  den0 += __shfl_xor(den0, 32, 64);
  den1 += __shfl_xor(den1, 16, 64);
  den1 += __shfl_xor(den1, 32, 64);
  if (hq == 0) {
    long drow = ((long)(sp * BB + b)) * NN + i0 + ln;
    pden[drow * LL + l0] = den0;
    pden[drow * LL + l1] = den1;
  }
}

// ---------------- Kernel C: combine partials ----------------
__global__ __launch_bounds__(256) void reduce_kernel(
    const float* __restrict__ pnum, const float* __restrict__ pden,
    float* __restrict__ out)
{
  int e4 = blockIdx.x * 256 + threadIdx.x;   // float4 index
  int bi = e4 >> 5;                          // token 0..8191
  int l = (e4 & 31) >> 2;
  const float4* p4 = (const float4*)pnum;
  float4 n0 = p4[e4];
  float4 n1 = p4[e4 + (BB * NN * CC / 4)];
  float den = pden[(long)bi * LL + l] + pden[((long)BB * NN + bi) * LL + l];
  float inv = 1.0f / den;
  float4 o;
  o.x = (n0.x + n1.x) * inv;
  o.y = (n0.y + n1.y) * inv;
  o.z = (n0.z + n1.z) * inv;
  o.w = (n0.w + n1.w) * inv;
  ((float4*)out)[e4] = o;
}

extern "C" void kernel_launch(void* const* d_in, const int* in_sizes, int n_in,
                              void* d_out, int out_size, void* d_ws, size_t ws_size,
                              hipStream_t stream) {
  const float* x         = (const float*)d_in[0];
  const float* masks     = (const float*)d_in[1];
  const float* Wq        = (const float*)d_in[2];
  const float* Wk        = (const float*)d_in[3];
  const float* Wv        = (const float*)d_in[4];
  const float* mask_proj = (const float*)d_in[5];
  float* out = (float*)d_out;

  // ws bytes: qb 1M | kb 1M | vtb 2M | pnum 8M | pden 0.5M = 12.5 MB
  // (ws poison costs ~1 us/MB per iteration -- keep this small)
  char* wsB = (char*)d_ws;
  short* qb   = (short*)(wsB);
  short* kb   = (short*)(wsB + (1l << 20));
  short* vtb  = (short*)(wsB + (2l << 20));
  float* pnum = (float*)(wsB + (4l << 20));
  float* pden = (float*)(wsB + (12l << 20));

  proj_kernel<<<512, 256, 0, stream>>>(x, Wq, Wk, Wv, qb, kb, vtb);
  attn_kernel<<<BB * (NN / IT) * SPLIT, 256, 0, stream>>>(qb, kb, vtb, masks,
                                                          mask_proj, pnum, pden);
  reduce_kernel<<<(BB * NN * CC / 4) / 256, 256, 0, stream>>>(pnum, pden, out);
}

// Round 15
// 137.838 us; speedup vs baseline: 1.0845x; 1.0845x over previous
//
#include <hip/hip_runtime.h>

#define BB 8
#define NN 1024
#define CC 128
#define GG 4
#define LL 8
#define GD 64

typedef __attribute__((ext_vector_type(8))) short short8;
typedef __attribute__((ext_vector_type(4))) short short4v;
typedef __attribute__((ext_vector_type(4))) float floatx4;

__device__ __forceinline__ short f2b(float f) {
  union { float f; unsigned u; } c; c.f = f;
  unsigned u = c.u;
  return (short)((u + 0x7FFFu + ((u >> 16) & 1u)) >> 16);   // RNE fp32->bf16
}
__device__ __forceinline__ float b2f(short s) {
  union { unsigned u; float f; } c; c.u = ((unsigned)(unsigned short)s) << 16;
  return c.f;
}
__device__ __forceinline__ void split2(float v, short& hi, short& lo) {
  short h = f2b(v);
  hi = h;
  lo = f2b(v - b2f(h));
}

// packed fp32x2 -> bf16x2 (dword: low=a, high=b)
#if __has_builtin(__builtin_amdgcn_cvt_pk_bf16_f32)
__device__ __forceinline__ unsigned pk2(float a, float b) {
  auto r = __builtin_amdgcn_cvt_pk_bf16_f32(a, b);
  unsigned u; __builtin_memcpy(&u, &r, 4); return u;
}
#else
__device__ __forceinline__ unsigned pk2(float a, float b) {
  return (unsigned)(unsigned short)f2b(a) | ((unsigned)(unsigned short)f2b(b) << 16);
}
#endif

#if __has_builtin(__builtin_amdgcn_exp2f)
#define EXP2(x) __builtin_amdgcn_exp2f(x)
#else
#define EXP2(x) exp2f(x)
#endif

// async global->LDS, 16B per lane, dest = base + lane*16 (linear)
#if __has_builtin(__builtin_amdgcn_global_load_lds)
__device__ __forceinline__ void gll16(const void* g, void* l, int lane) {
  (void)lane;
  __builtin_amdgcn_global_load_lds(
      (const __attribute__((address_space(1))) unsigned int*)g,
      (__attribute__((address_space(3))) unsigned int*)l, 16, 0, 0);
}
#else
__device__ __forceinline__ void gll16(const void* g, void* l, int lane) {
  uint4 t = *(const uint4*)g;
  *(uint4*)((char*)l + lane * 16) = t;
}
#endif

// ---------------- Kernel A: projections, W hi/lo-split staged in LDS ------
#define BHP 136   // shorts per W row in LDS; 68 dwords, 68%32=4 -> 2-way free

__global__ __launch_bounds__(256) void proj_kernel(
    const float* __restrict__ x, const float* __restrict__ Wq,
    const float* __restrict__ Wk, const float* __restrict__ Wv,
    short* __restrict__ qb, short* __restrict__ kb, short* __restrict__ vtb)
{
  __shared__ short bh[64 * BHP];   // 17408 B
  __shared__ short bl[64 * BHP];   // 17408 B
  const int t = threadIdx.x;
  const int nt = blockIdx.x & 3;
  const int mt = blockIdx.x >> 2;
  const int w = t >> 6;
  const int lane = t & 63;
  const int ln = lane & 15;
  const int hq = lane >> 4;
  const int arow = mt * 64 + w * 16 + ln;

  const float* wbase = (nt == 0) ? Wq : (nt == 1) ? Wk : (Wv + (nt - 2) * 64 * 128);

  // stage + split W: thread -> row t>>2, cols (t&3)*32..+31
  {
    int r = t >> 2, c0 = (t & 3) * 32;
    const float* src = wbase + r * 128 + c0;
    #pragma unroll
    for (int z8 = 0; z8 < 4; ++z8) {
      float4 u0 = *(const float4*)(src + z8 * 8);
      float4 u1 = *(const float4*)(src + z8 * 8 + 4);
      float uv[8] = {u0.x,u0.y,u0.z,u0.w,u1.x,u1.y,u1.z,u1.w};
      union { short s[8]; short8 v; } H, L;
      #pragma unroll
      for (int z = 0; z < 8; ++z) split2(uv[z], H.s[z], L.s[z]);
      *(short8*)(bh + r * BHP + c0 + z8 * 8) = H.v;
      *(short8*)(bl + r * BHP + c0 + z8 * 8) = L.v;
    }
  }
  __syncthreads();

  const floatx4 zf = {0.f, 0.f, 0.f, 0.f};
  floatx4 acc[4] = {zf, zf, zf, zf};

  #pragma unroll
  for (int kc = 0; kc < 4; ++kc) {
    const float* xp = x + (long)arow * 128 + kc * 32 + hq * 8;
    float4 a0 = *(const float4*)xp;
    float4 a1 = *(const float4*)(xp + 4);
    union { short s[8]; short8 v; } Ah, Al;
    float av[8] = {a0.x,a0.y,a0.z,a0.w,a1.x,a1.y,a1.z,a1.w};
    #pragma unroll
    for (int z = 0; z < 8; ++z) split2(av[z], Ah.s[z], Al.s[z]);
    #pragma unroll
    for (int ns = 0; ns < 4; ++ns) {
      short8 Bh = *(const short8*)(bh + (ns * 16 + ln) * BHP + kc * 32 + hq * 8);
      short8 Bl = *(const short8*)(bl + (ns * 16 + ln) * BHP + kc * 32 + hq * 8);
      acc[ns] = __builtin_amdgcn_mfma_f32_16x16x32_bf16(Ah.v, Bh, acc[ns], 0,0,0);
      acc[ns] = __builtin_amdgcn_mfma_f32_16x16x32_bf16(Al.v, Bh, acc[ns], 0,0,0);
      acc[ns] = __builtin_amdgcn_mfma_f32_16x16x32_bf16(Ah.v, Bl, acc[ns], 0,0,0);
    }
  }

  if (nt < 2) {
    short* dst = (nt == 0) ? qb : kb;
    #pragma unroll
    for (int ns = 0; ns < 4; ++ns) {
      int col = ns * 16 + ln;
      #pragma unroll
      for (int reg = 0; reg < 4; ++reg) {
        int row = mt * 64 + w * 16 + hq * 4 + reg;
        dst[(long)row * 64 + col] = f2b(acc[ns][reg]);
      }
    }
  } else {
    int b = mt >> 4;
    int tok = (mt * 64 + w * 16 + hq * 4) & 1023;
    #pragma unroll
    for (int ns = 0; ns < 4; ++ns) {
      int cv = (nt - 2) * 64 + ns * 16 + ln;
      union { short s[4]; short4v v; } o;
      #pragma unroll
      for (int reg = 0; reg < 4; ++reg) o.s[reg] = f2b(acc[ns][reg]);
      *(short4v*)(vtb + ((long)b * CC + cv) * NN + tok) = o.v;
    }
  }
}

// ---------------- Kernel B: 8-wave SPLIT=1, fused normalize --------------
// grid 512 (2 blocks/CU, 16 waves/CU): itile = bx&63, b = bx>>6.
// 512 threads = 8 waves. Per 64-j tile (16 tiles, full j-range):
//   barA (drains K-gll) | waves 0-3: QK<-kbuf (g=w, r9 form);
//   waves 4-7: stage masks->mrec | barB | all: gll next K | mix (l=w).
// den complete per block -> normalize in epilogue, write final out.
// No pnum/pden/reduce kernel; ws shrinks 12.5->4MB (poison -8.5us).
#define IT 16
#define JT 64
#define NTL 16
#define ARP 260   // dwords per i-row of arec: arec[i][j*4+g]
#define MRP 196   // dwords per i-row of mrec: mrec[i][j*3+m]

__global__ __launch_bounds__(512, 4) void attn_kernel(
    const short* __restrict__ qb, const short* __restrict__ kb,
    const short* __restrict__ vtb, const float* __restrict__ masks,
    const float* __restrict__ mask_proj,
    float* __restrict__ out)
{
  __shared__ float arec[IT * ARP];   // 16640 B
  __shared__ float mrec[IT * MRP];   // 12544 B
  __shared__ short kbuf[64 * 64];    //  8192 B   (37376 B total)

  const int t = threadIdx.x;
  const int itile = blockIdx.x & 63;
  const int b = blockIdx.x >> 6;
  const int i0 = itile * IT;

  const int w = t >> 6;          // wave id 0..7: QK g (w<4) / stage (w>=4); mix l=w
  const int lane = t & 63;
  const int ln = lane & 15;
  const int hq = lane >> 4;
  const int t2 = t & 255;        // staging thread index within waves 4-7

  // Q A-fragment (g = w) for QK waves only; K-dim zero-padded 16->32
  short8 qf;
  {
    union { short s[8]; short8 v; } qq;
    #pragma unroll
    for (int z = 0; z < 8; ++z) qq.s[z] = 0;
    if (w < 4 && hq < 2)
      qq.v = *(const short8*)(qb + ((long)(b * NN + i0 + ln)) * GD + w * 16 + hq * 8);
    qf = qq.v;
  }
  // mix constants for l = w, folded into exp2 domain
  const float LOG2E = 1.44269504088896340736f;
  float ycA[3][4];
  #pragma unroll
  for (int m = 0; m < 3; ++m)
    #pragma unroll
    for (int g = 0; g < 4; ++g)
      ycA[m][g] = mask_proj[m * 32 + g * 8 + w] * LOG2E;

  const floatx4 zf = {0.f, 0.f, 0.f, 0.f};
  floatx4 pv0 = zf;
  float den0 = 0.f;

  const short* kbase = kb + (long)b * NN * GD;
  const short* v0base = vtb + ((long)b * CC + w * 16 + ln) * NN;

  // K-prefetch per-lane constants: wave w stages row-group I = w
  const int klj = lane >> 3;              // row within 8-row group
  const int ke8 = (lane & 7) ^ klj;       // source d-octet (XOR pre-swizzle)

  // prologue: prefetch tile 0's K into kbuf (drained by first barA)
  gll16(kbase + (long)(w * 8 + klj) * GD + ke8 * 8, kbuf + w * 512, lane);

  for (int jt = 0; jt < NTL; ++jt) {
    const int j0 = jt * JT;
    __syncthreads();   // barA: prev mix readers done + K-gll drained (vmcnt 0)

    if (w >= 4) {
      // ---- stage masks 16i x 64j x 3 (768 float4, coalesced) ----
      #pragma unroll
      for (int it2 = 0; it2 < 3; ++it2) {
        int f = t2 + it2 * 256;
        int ii = f / 48;
        int rem = f - ii * 48;
        *(float4*)(mrec + ii * MRP + rem * 4) =
          *(const float4*)(masks + (long)(i0 + ii) * (NN * 3) + (long)j0 * 3 + rem * 4);
      }
    } else {
      // ---- QK: wave g = w, K from kbuf (XOR-chunk layout, r9 form) ----
      #pragma unroll
      for (int jsub = 0; jsub < 4; ++jsub) {
        union { short s[8]; short8 v; } kk;
        #pragma unroll
        for (int z = 0; z < 8; ++z) kk.s[z] = 0;
        if (hq < 2) {
          const int jloc = jsub * 16 + ln;
          kk.v = *(const short8*)(kbuf + jloc * 64 + (((w * 2 + hq) ^ (jloc & 7)) << 3));
        }
        floatx4 at = __builtin_amdgcn_mfma_f32_16x16x32_bf16(qf, kk.v, zf, 0, 0, 0);
        float* ab = arec + (jsub * 16 + ln) * 4 + w;     // arec[i][j*4+g]
        #pragma unroll
        for (int reg = 0; reg < 4; ++reg)
          ab[(hq * 4 + reg) * ARP] = at[reg];
      }
    }
    __syncthreads();   // barB: mrec + arec ready; all kbuf reads done

    // ---- issue NEXT tile's K prefetch (lands under the mix phase) ----
    {
      const int jn = ((jt + 1) & (NTL - 1)) * JT;
      gll16(kbase + (long)(jn + w * 8 + klj) * GD + ke8 * 8, kbuf + w * 512, lane);
    }

    // ---- mix + exp2 + PV: thread = (i=ln, j-octet=hq), l = w ----
    #pragma unroll
    for (int mf = 0; mf < 2; ++mf) {
      float mku[24];
      {
        const float* mb = mrec + ln * MRP + mf * 96 + hq * 24;
        #pragma unroll
        for (int q4 = 0; q4 < 6; ++q4)
          *(float4*)(mku + q4 * 4) = *(const float4*)(mb + q4 * 4);
      }
      short8 vf0 = *(const short8*)(v0base + j0 + mf * 32 + hq * 8);
      const float* arA = arec + ln * ARP + (mf * 32 + hq * 8) * 4;
      union { unsigned u[4]; short8 v; } p0;
      #pragma unroll
      for (int zp = 0; zp < 4; ++zp) {
        float eA[2];
        #pragma unroll
        for (int zz = 0; zz < 2; ++zz) {
          int z = zp * 2 + zz;
          floatx4 a4 = *(const floatx4*)(arA + z * 4);
          float m0 = mku[z * 3], m1 = mku[z * 3 + 1], m2 = mku[z * 3 + 2];
          float wA0 = m0*ycA[0][0] + m1*ycA[1][0] + m2*ycA[2][0];
          float wA1 = m0*ycA[0][1] + m1*ycA[1][1] + m2*ycA[2][1];
          float wA2 = m0*ycA[0][2] + m1*ycA[1][2] + m2*ycA[2][2];
          float wA3 = m0*ycA[0][3] + m1*ycA[1][3] + m2*ycA[2][3];
          float sA = a4[0]*wA0 + a4[1]*wA1 + a4[2]*wA2 + a4[3]*wA3;
          eA[zz] = EXP2(sA);
        }
        den0 += eA[0] + eA[1];
        p0.u[zp] = pk2(eA[0], eA[1]);
      }
      pv0 = __builtin_amdgcn_mfma_f32_16x16x32_bf16(p0.v, vf0, pv0, 0, 0, 0);
    }
  }

  // ---- epilogue: butterfly den over hq (all lanes get den(i=ln)),
  //      align den to pv rows via shfl, normalize, write final out ----
  den0 += __shfl_xor(den0, 16, 64);
  den0 += __shfl_xor(den0, 32, 64);
  #pragma unroll
  for (int reg = 0; reg < 4; ++reg) {
    float d = __shfl(den0, hq * 4 + reg, 64);   // den for i = hq*4+reg
    long row = (long)(b * NN + i0 + hq * 4 + reg);
    out[row * CC + w * 16 + ln] = pv0[reg] / d;
  }
}

extern "C" void kernel_launch(void* const* d_in, const int* in_sizes, int n_in,
                              void* d_out, int out_size, void* d_ws, size_t ws_size,
                              hipStream_t stream) {
  const float* x         = (const float*)d_in[0];
  const float* masks     = (const float*)d_in[1];
  const float* Wq        = (const float*)d_in[2];
  const float* Wk        = (const float*)d_in[3];
  const float* Wv        = (const float*)d_in[4];
  const float* mask_proj = (const float*)d_in[5];
  float* out = (float*)d_out;

  // ws bytes: qb 1M | kb 1M | vtb 2M = 4 MB total
  // (ws poison costs ~1 us/MB per iteration -- keep this small)
  char* wsB = (char*)d_ws;
  short* qb   = (short*)(wsB);
  short* kb   = (short*)(wsB + (1l << 20));
  short* vtb  = (short*)(wsB + (2l << 20));

  proj_kernel<<<512, 256, 0, stream>>>(x, Wq, Wk, Wv, qb, kb, vtb);
  attn_kernel<<<BB * (NN / IT), 512, 0, stream>>>(qb, kb, vtb, masks,
                                                  mask_proj, out);
}

// Round 17
// 127.775 us; speedup vs baseline: 1.1699x; 1.0788x over previous
//
#include <hip/hip_runtime.h>

#define BB 8
#define NN 1024
#define CC 128
#define GG 4
#define LL 8
#define GD 64

typedef __attribute__((ext_vector_type(8))) short short8;
typedef __attribute__((ext_vector_type(4))) short short4v;
typedef __attribute__((ext_vector_type(4))) float floatx4;

__device__ __forceinline__ short f2b(float f) {
  union { float f; unsigned u; } c; c.f = f;
  unsigned u = c.u;
  return (short)((u + 0x7FFFu + ((u >> 16) & 1u)) >> 16);   // RNE fp32->bf16
}
__device__ __forceinline__ float b2f(short s) {
  union { unsigned u; float f; } c; c.u = ((unsigned)(unsigned short)s) << 16;
  return c.f;
}
__device__ __forceinline__ void split2(float v, short& hi, short& lo) {
  short h = f2b(v);
  hi = h;
  lo = f2b(v - b2f(h));
}

// packed fp32x2 -> bf16x2 (dword: low=a, high=b)
#if __has_builtin(__builtin_amdgcn_cvt_pk_bf16_f32)
__device__ __forceinline__ unsigned pk2(float a, float b) {
  auto r = __builtin_amdgcn_cvt_pk_bf16_f32(a, b);
  unsigned u; __builtin_memcpy(&u, &r, 4); return u;
}
#else
__device__ __forceinline__ unsigned pk2(float a, float b) {
  return (unsigned)(unsigned short)f2b(a) | ((unsigned)(unsigned short)f2b(b) << 16);
}
#endif

#if __has_builtin(__builtin_amdgcn_exp2f)
#define EXP2(x) __builtin_amdgcn_exp2f(x)
#else
#define EXP2(x) exp2f(x)
#endif

// async global->LDS, 16B per lane, dest = base + lane*16 (linear)
#if __has_builtin(__builtin_amdgcn_global_load_lds)
__device__ __forceinline__ void gll16(const void* g, void* l, int lane) {
  (void)lane;
  __builtin_amdgcn_global_load_lds(
      (const __attribute__((address_space(1))) unsigned int*)g,
      (__attribute__((address_space(3))) unsigned int*)l, 16, 0, 0);
}
#else
__device__ __forceinline__ void gll16(const void* g, void* l, int lane) {
  uint4 t = *(const uint4*)g;
  *(uint4*)((char*)l + lane * 16) = t;
}
#endif

// ---------------- Kernel A: projections, W hi/lo-split staged in LDS ------
#define BHP 136   // shorts per W row in LDS; 68 dwords, 68%32=4 -> 2-way free

__global__ __launch_bounds__(256) void proj_kernel(
    const float* __restrict__ x, const float* __restrict__ Wq,
    const float* __restrict__ Wk, const float* __restrict__ Wv,
    short* __restrict__ qb, short* __restrict__ kb, short* __restrict__ vtb)
{
  __shared__ short bh[64 * BHP];   // 17408 B
  __shared__ short bl[64 * BHP];   // 17408 B
  const int t = threadIdx.x;
  const int nt = blockIdx.x & 3;
  const int mt = blockIdx.x >> 2;
  const int w = t >> 6;
  const int lane = t & 63;
  const int ln = lane & 15;
  const int hq = lane >> 4;
  const int arow = mt * 64 + w * 16 + ln;

  const float* wbase = (nt == 0) ? Wq : (nt == 1) ? Wk : (Wv + (nt - 2) * 64 * 128);

  // stage + split W: thread -> row t>>2, cols (t&3)*32..+31
  {
    int r = t >> 2, c0 = (t & 3) * 32;
    const float* src = wbase + r * 128 + c0;
    #pragma unroll
    for (int z8 = 0; z8 < 4; ++z8) {
      float4 u0 = *(const float4*)(src + z8 * 8);
      float4 u1 = *(const float4*)(src + z8 * 8 + 4);
      float uv[8] = {u0.x,u0.y,u0.z,u0.w,u1.x,u1.y,u1.z,u1.w};
      union { short s[8]; short8 v; } H, L;
      #pragma unroll
      for (int z = 0; z < 8; ++z) split2(uv[z], H.s[z], L.s[z]);
      *(short8*)(bh + r * BHP + c0 + z8 * 8) = H.v;
      *(short8*)(bl + r * BHP + c0 + z8 * 8) = L.v;
    }
  }
  __syncthreads();

  const floatx4 zf = {0.f, 0.f, 0.f, 0.f};
  floatx4 acc[4] = {zf, zf, zf, zf};

  #pragma unroll
  for (int kc = 0; kc < 4; ++kc) {
    const float* xp = x + (long)arow * 128 + kc * 32 + hq * 8;
    float4 a0 = *(const float4*)xp;
    float4 a1 = *(const float4*)(xp + 4);
    union { short s[8]; short8 v; } Ah, Al;
    float av[8] = {a0.x,a0.y,a0.z,a0.w,a1.x,a1.y,a1.z,a1.w};
    #pragma unroll
    for (int z = 0; z < 8; ++z) split2(av[z], Ah.s[z], Al.s[z]);
    #pragma unroll
    for (int ns = 0; ns < 4; ++ns) {
      short8 Bh = *(const short8*)(bh + (ns * 16 + ln) * BHP + kc * 32 + hq * 8);
      short8 Bl = *(const short8*)(bl + (ns * 16 + ln) * BHP + kc * 32 + hq * 8);
      acc[ns] = __builtin_amdgcn_mfma_f32_16x16x32_bf16(Ah.v, Bh, acc[ns], 0,0,0);
      acc[ns] = __builtin_amdgcn_mfma_f32_16x16x32_bf16(Al.v, Bh, acc[ns], 0,0,0);
      acc[ns] = __builtin_amdgcn_mfma_f32_16x16x32_bf16(Ah.v, Bl, acc[ns], 0,0,0);
    }
  }

  if (nt < 2) {
    short* dst = (nt == 0) ? qb : kb;
    #pragma unroll
    for (int ns = 0; ns < 4; ++ns) {
      int col = ns * 16 + ln;
      #pragma unroll
      for (int reg = 0; reg < 4; ++reg) {
        int row = mt * 64 + w * 16 + hq * 4 + reg;
        dst[(long)row * 64 + col] = f2b(acc[ns][reg]);
      }
    }
  } else {
    int b = mt >> 4;
    int tok = (mt * 64 + w * 16 + hq * 4) & 1023;
    #pragma unroll
    for (int ns = 0; ns < 4; ++ns) {
      int cv = (nt - 2) * 64 + ns * 16 + ln;
      union { short s[4]; short4v v; } o;
      #pragma unroll
      for (int reg = 0; reg < 4; ++reg) o.s[reg] = f2b(acc[ns][reg]);
      *(short4v*)(vtb + ((long)b * CC + cv) * NN + tok) = o.v;
    }
  }
}

// ---------------- Kernel B: r12 hot loop + K gll-prefetch into LDS --------
// grid 1024 (= 4 blocks/CU co-resident at 37376 B LDS):
// sp = bx&1, itile = (bx>>1)&63, b = bx>>7.
// Per 64-j tile: barA (drains K-gll) | stage masks + QK<-kbuf | barB |
// issue gll(K of jt+1 -> kbuf) | mix+PV (K latency hides under ~2000cy mix).
// kbuf chunk layout: byte(j,d8) = j*128 + ((d8 ^ (j&7))*16  (XOR spreads
// banks; gll dest is linear, so the XOR is applied to the GLOBAL source
// per-lane: lane fetches K[I*8 + (lane>>3)][8*((lane&7)^(lane>>3)) ..+7]).
#define IT 16
#define JT 64
#define SPLIT 2
#define JSPAN 512
#define NTL 8
#define ARP 260   // dwords per i-row of arec: arec[i][j*4+g]
#define MRP 196   // dwords per i-row of mrec: mrec[i][j*3+m]

__global__ __launch_bounds__(256, 3) void attn_kernel(
    const short* __restrict__ qb, const short* __restrict__ kb,
    const short* __restrict__ vtb, const float* __restrict__ masks,
    const float* __restrict__ mask_proj,
    float* __restrict__ pnum, float* __restrict__ pden)
{
  __shared__ float arec[IT * ARP];   // 16640 B
  __shared__ float mrec[IT * MRP];   // 12544 B
  __shared__ short kbuf[64 * 64];    //  8192 B   (37376 B total)

  const int t = threadIdx.x;
  const int sp = blockIdx.x & 1;
  const int itile = (blockIdx.x >> 1) & 63;
  const int b = blockIdx.x >> 7;
  const int i0 = itile * IT;

  const int w = t >> 6;          // wave id: g (QK) ; l-pair owner (mix+PV)
  const int lane = t & 63;
  const int ln = lane & 15;
  const int hq = lane >> 4;
  const int l0 = 2 * w, l1 = 2 * w + 1;

  // Q A-fragment (g = w), K-dim zero-padded 16->32 (hq>=2 lanes zero)
  short8 qf;
  {
    union { short s[8]; short8 v; } qq;
    #pragma unroll
    for (int z = 0; z < 8; ++z) qq.s[z] = 0;
    if (hq < 2)
      qq.v = *(const short8*)(qb + ((long)(b * NN + i0 + ln)) * GD + w * 16 + hq * 8);
    qf = qq.v;
  }
  // mix constants folded into exp2 domain
  const float LOG2E = 1.44269504088896340736f;
  float ycA[3][4], ycB[3][4];
  #pragma unroll
  for (int m = 0; m < 3; ++m)
    #pragma unroll
    for (int g = 0; g < 4; ++g) {
      ycA[m][g] = mask_proj[m * 32 + g * 8 + l0] * LOG2E;
      ycB[m][g] = mask_proj[m * 32 + g * 8 + l1] * LOG2E;
    }

  const floatx4 zf = {0.f, 0.f, 0.f, 0.f};
  floatx4 pv0 = zf, pv1 = zf;
  float den0 = 0.f, den1 = 0.f;

  const short* kbase = kb + (long)b * NN * GD;
  const short* v0base = vtb + ((long)b * CC + l0 * 16 + ln) * NN;
  const short* v1base = vtb + ((long)b * CC + l1 * 16 + ln) * NN;

  // K-prefetch per-lane constants: wave w stages row-groups I = w*2, w*2+1
  const int klj = lane >> 3;              // row within 8-row group
  const int ke8 = (lane & 7) ^ klj;       // source d-octet (XOR pre-swizzle)

  // prologue: prefetch tile 0's K into kbuf (drained by first barA)
  #pragma unroll
  for (int ii = 0; ii < 2; ++ii) {
    const int I = w * 2 + ii;
    gll16(kbase + (long)(sp * JSPAN + I * 8 + klj) * GD + ke8 * 8,
          kbuf + I * 512, lane);
  }

  for (int jt = 0; jt < NTL; ++jt) {
    const int j0 = sp * JSPAN + jt * JT;
    __syncthreads();   // barA: prev mix readers done + K-gll drained (vmcnt 0)

    // ---- stage masks 16i x 64j x 3 (768 float4, coalesced) ----
    #pragma unroll
    for (int it2 = 0; it2 < 3; ++it2) {
      int f = t + it2 * 256;
      int ii = f / 48;
      int rem = f - ii * 48;
      *(float4*)(mrec + ii * MRP + rem * 4) =
        *(const float4*)(masks + (long)(i0 + ii) * (NN * 3) + (long)j0 * 3 + rem * 4);
    }
    // ---- QK: wave g = w, K from kbuf (XOR-chunk layout) ----
    #pragma unroll
    for (int jsub = 0; jsub < 4; ++jsub) {
      union { short s[8]; short8 v; } kk;
      #pragma unroll
      for (int z = 0; z < 8; ++z) kk.s[z] = 0;
      if (hq < 2) {
        const int jloc = jsub * 16 + ln;
        kk.v = *(const short8*)(kbuf + jloc * 64 + (((w * 2 + hq) ^ (jloc & 7)) << 3));
      }
      floatx4 at = __builtin_amdgcn_mfma_f32_16x16x32_bf16(qf, kk.v, zf, 0, 0, 0);
      float* ab = arec + (jsub * 16 + ln) * 4 + w;     // arec[i][j*4+g]
      #pragma unroll
      for (int reg = 0; reg < 4; ++reg)
        ab[(hq * 4 + reg) * ARP] = at[reg];
    }
    __syncthreads();   // barB: mrec + arec ready; all kbuf reads done

    // ---- issue NEXT tile's K prefetch (lands under the mix phase) ----
    {
      const int jn = sp * JSPAN + ((jt + 1) & (NTL - 1)) * JT;
      #pragma unroll
      for (int ii = 0; ii < 2; ++ii) {
        const int I = w * 2 + ii;
        gll16(kbase + (long)(jn + I * 8 + klj) * GD + ke8 * 8,
              kbuf + I * 512, lane);
      }
    }

    // ---- mix + exp2 + PV: thread = (i=ln, j-octet=hq), l = 2w, 2w+1 ----
    #pragma unroll
    for (int mf = 0; mf < 2; ++mf) {
      float mku[24];
      {
        const float* mb = mrec + ln * MRP + mf * 96 + hq * 24;
        #pragma unroll
        for (int q4 = 0; q4 < 6; ++q4)
          *(float4*)(mku + q4 * 4) = *(const float4*)(mb + q4 * 4);
      }
      short8 vf0 = *(const short8*)(v0base + j0 + mf * 32 + hq * 8);
      short8 vf1 = *(const short8*)(v1base + j0 + mf * 32 + hq * 8);
      const float* arA = arec + ln * ARP + (mf * 32 + hq * 8) * 4;
      union { unsigned u[4]; short8 v; } p0, p1;
      #pragma unroll
      for (int zp = 0; zp < 4; ++zp) {
        float eA[2], eB[2];
        #pragma unroll
        for (int zz = 0; zz < 2; ++zz) {
          int z = zp * 2 + zz;
          floatx4 a4 = *(const floatx4*)(arA + z * 4);
          float m0 = mku[z * 3], m1 = mku[z * 3 + 1], m2 = mku[z * 3 + 2];
          float wA0 = m0*ycA[0][0] + m1*ycA[1][0] + m2*ycA[2][0];
          float wA1 = m0*ycA[0][1] + m1*ycA[1][1] + m2*ycA[2][1];
          float wA2 = m0*ycA[0][2] + m1*ycA[1][2] + m2*ycA[2][2];
          float wA3 = m0*ycA[0][3] + m1*ycA[1][3] + m2*ycA[2][3];
          float wB0 = m0*ycB[0][0] + m1*ycB[1][0] + m2*ycB[2][0];
          float wB1 = m0*ycB[0][1] + m1*ycB[1][1] + m2*ycB[2][1];
          float wB2 = m0*ycB[0][2] + m1*ycB[1][2] + m2*ycB[2][2];
          float wB3 = m0*ycB[0][3] + m1*ycB[1][3] + m2*ycB[2][3];
          float sA = a4[0]*wA0 + a4[1]*wA1 + a4[2]*wA2 + a4[3]*wA3;
          float sB = a4[0]*wB0 + a4[1]*wB1 + a4[2]*wB2 + a4[3]*wB3;
          eA[zz] = EXP2(sA);
          eB[zz] = EXP2(sB);
        }
        den0 += eA[0] + eA[1];
        den1 += eB[0] + eB[1];
        p0.u[zp] = pk2(eA[0], eA[1]);
        p1.u[zp] = pk2(eB[0], eB[1]);
      }
      pv0 = __builtin_amdgcn_mfma_f32_16x16x32_bf16(p0.v, vf0, pv0, 0, 0, 0);
      pv1 = __builtin_amdgcn_mfma_f32_16x16x32_bf16(p1.v, vf1, pv1, 0, 0, 0);
    }
  }

  // ---- epilogue: partial numerators; den reduced over hq via shuffles ----
  #pragma unroll
  for (int reg = 0; reg < 4; ++reg) {
    long row = ((long)(sp * BB + b)) * NN + i0 + hq * 4 + reg;
    pnum[row * CC + l0 * 16 + ln] = pv0[reg];
    pnum[row * CC + l1 * 16 + ln] = pv1[reg];
  }
  // sum den over the 4 hq lanes (stride-16 within the wave)
  den0 += __shfl_xor(den0, 16, 64);
  den0 += __shfl_xor(den0, 32, 64);
  den1 += __shfl_xor(den1, 16, 64);
  den1 += __shfl_xor(den1, 32, 64);
  if (hq == 0) {
    long drow = ((long)(sp * BB + b)) * NN + i0 + ln;
    pden[drow * LL + l0] = den0;
    pden[drow * LL + l1] = den1;
  }
}

// ---------------- Kernel C: combine partials ----------------
__global__ __launch_bounds__(256) void reduce_kernel(
    const float* __restrict__ pnum, const float* __restrict__ pden,
    float* __restrict__ out)
{
  int e4 = blockIdx.x * 256 + threadIdx.x;   // float4 index
  int bi = e4 >> 5;                          // token 0..8191
  int l = (e4 & 31) >> 2;
  const float4* p4 = (const float4*)pnum;
  float4 n0 = p4[e4];
  float4 n1 = p4[e4 + (BB * NN * CC / 4)];
  float den = pden[(long)bi * LL + l] + pden[((long)BB * NN + bi) * LL + l];
  float inv = 1.0f / den;
  float4 o;
  o.x = (n0.x + n1.x) * inv;
  o.y = (n0.y + n1.y) * inv;
  o.z = (n0.z + n1.z) * inv;
  o.w = (n0.w + n1.w) * inv;
  ((float4*)out)[e4] = o;
}

extern "C" void kernel_launch(void* const* d_in, const int* in_sizes, int n_in,
                              void* d_out, int out_size, void* d_ws, size_t ws_size,
                              hipStream_t stream) {
  const float* x         = (const float*)d_in[0];
  const float* masks     = (const float*)d_in[1];
  const float* Wq        = (const float*)d_in[2];
  const float* Wk        = (const float*)d_in[3];
  const float* Wv        = (const float*)d_in[4];
  const float* mask_proj = (const float*)d_in[5];
  float* out = (float*)d_out;

  // ws bytes: qb 1M | kb 1M | vtb 2M | pnum 8M | pden 0.5M = 12.5 MB
  // (ws poison costs ~1 us/MB per iteration -- keep this small)
  char* wsB = (char*)d_ws;
  short* qb   = (short*)(wsB);
  short* kb   = (short*)(wsB + (1l << 20));
  short* vtb  = (short*)(wsB + (2l << 20));
  float* pnum = (float*)(wsB + (4l << 20));
  float* pden = (float*)(wsB + (12l << 20));

  proj_kernel<<<512, 256, 0, stream>>>(x, Wq, Wk, Wv, qb, kb, vtb);
  attn_kernel<<<BB * (NN / IT) * SPLIT, 256, 0, stream>>>(qb, kb, vtb, masks,
                                                          mask_proj, pnum, pden);
  reduce_kernel<<<(BB * NN * CC / 4) / 256, 256, 0, stream>>>(pnum, pden, out);
}

// Round 18
// 123.378 us; speedup vs baseline: 1.2116x; 1.0356x over previous
//
#include <hip/hip_runtime.h>

#define BB 8
#define NN 1024
#define CC 128
#define GG 4
#define LL 8
#define GD 64

typedef __attribute__((ext_vector_type(8))) short short8;
typedef __attribute__((ext_vector_type(4))) short short4v;
typedef __attribute__((ext_vector_type(4))) float floatx4;
typedef __attribute__((ext_vector_type(2))) float float2v;

__device__ __forceinline__ short f2b(float f) {
  union { float f; unsigned u; } c; c.f = f;
  unsigned u = c.u;
  return (short)((u + 0x7FFFu + ((u >> 16) & 1u)) >> 16);   // RNE fp32->bf16
}
__device__ __forceinline__ float b2f(short s) {
  union { unsigned u; float f; } c; c.u = ((unsigned)(unsigned short)s) << 16;
  return c.f;
}
__device__ __forceinline__ void split2(float v, short& hi, short& lo) {
  short h = f2b(v);
  hi = h;
  lo = f2b(v - b2f(h));
}

// packed fp32x2 -> bf16x2 (dword: low=a, high=b)
#if __has_builtin(__builtin_amdgcn_cvt_pk_bf16_f32)
__device__ __forceinline__ unsigned pk2(float a, float b) {
  auto r = __builtin_amdgcn_cvt_pk_bf16_f32(a, b);
  unsigned u; __builtin_memcpy(&u, &r, 4); return u;
}
#else
__device__ __forceinline__ unsigned pk2(float a, float b) {
  return (unsigned)(unsigned short)f2b(a) | ((unsigned)(unsigned short)f2b(b) << 16);
}
#endif

#if __has_builtin(__builtin_amdgcn_exp2f)
#define EXP2(x) __builtin_amdgcn_exp2f(x)
#else
#define EXP2(x) exp2f(x)
#endif

// async global->LDS, 16B per lane, dest = base + lane*16 (linear)
#if __has_builtin(__builtin_amdgcn_global_load_lds)
__device__ __forceinline__ void gll16(const void* g, void* l, int lane) {
  (void)lane;
  __builtin_amdgcn_global_load_lds(
      (const __attribute__((address_space(1))) unsigned int*)g,
      (__attribute__((address_space(3))) unsigned int*)l, 16, 0, 0);
}
#else
__device__ __forceinline__ void gll16(const void* g, void* l, int lane) {
  uint4 t = *(const uint4*)g;
  *(uint4*)((char*)l + lane * 16) = t;
}
#endif

// ---------------- Kernel A: projections, W hi/lo-split staged in LDS ------
#define BHP 136   // shorts per W row in LDS; 68 dwords, 68%32=4 -> 2-way free

__global__ __launch_bounds__(256) void proj_kernel(
    const float* __restrict__ x, const float* __restrict__ Wq,
    const float* __restrict__ Wk, const float* __restrict__ Wv,
    short* __restrict__ qb, short* __restrict__ kb, short* __restrict__ vtb)
{
  __shared__ short bh[64 * BHP];   // 17408 B
  __shared__ short bl[64 * BHP];   // 17408 B
  const int t = threadIdx.x;
  const int nt = blockIdx.x & 3;
  const int mt = blockIdx.x >> 2;
  const int w = t >> 6;
  const int lane = t & 63;
  const int ln = lane & 15;
  const int hq = lane >> 4;
  const int arow = mt * 64 + w * 16 + ln;

  const float* wbase = (nt == 0) ? Wq : (nt == 1) ? Wk : (Wv + (nt - 2) * 64 * 128);

  // stage + split W: thread -> row t>>2, cols (t&3)*32..+31
  {
    int r = t >> 2, c0 = (t & 3) * 32;
    const float* src = wbase + r * 128 + c0;
    #pragma unroll
    for (int z8 = 0; z8 < 4; ++z8) {
      float4 u0 = *(const float4*)(src + z8 * 8);
      float4 u1 = *(const float4*)(src + z8 * 8 + 4);
      float uv[8] = {u0.x,u0.y,u0.z,u0.w,u1.x,u1.y,u1.z,u1.w};
      union { short s[8]; short8 v; } H, L;
      #pragma unroll
      for (int z = 0; z < 8; ++z) split2(uv[z], H.s[z], L.s[z]);
      *(short8*)(bh + r * BHP + c0 + z8 * 8) = H.v;
      *(short8*)(bl + r * BHP + c0 + z8 * 8) = L.v;
    }
  }
  __syncthreads();

  const floatx4 zf = {0.f, 0.f, 0.f, 0.f};
  floatx4 acc[4] = {zf, zf, zf, zf};

  #pragma unroll
  for (int kc = 0; kc < 4; ++kc) {
    const float* xp = x + (long)arow * 128 + kc * 32 + hq * 8;
    float4 a0 = *(const float4*)xp;
    float4 a1 = *(const float4*)(xp + 4);
    union { short s[8]; short8 v; } Ah, Al;
    float av[8] = {a0.x,a0.y,a0.z,a0.w,a1.x,a1.y,a1.z,a1.w};
    #pragma unroll
    for (int z = 0; z < 8; ++z) split2(av[z], Ah.s[z], Al.s[z]);
    #pragma unroll
    for (int ns = 0; ns < 4; ++ns) {
      short8 Bh = *(const short8*)(bh + (ns * 16 + ln) * BHP + kc * 32 + hq * 8);
      short8 Bl = *(const short8*)(bl + (ns * 16 + ln) * BHP + kc * 32 + hq * 8);
      acc[ns] = __builtin_amdgcn_mfma_f32_16x16x32_bf16(Ah.v, Bh, acc[ns], 0,0,0);
      acc[ns] = __builtin_amdgcn_mfma_f32_16x16x32_bf16(Al.v, Bh, acc[ns], 0,0,0);
      acc[ns] = __builtin_amdgcn_mfma_f32_16x16x32_bf16(Ah.v, Bl, acc[ns], 0,0,0);
    }
  }

  if (nt < 2) {
    short* dst = (nt == 0) ? qb : kb;
    #pragma unroll
    for (int ns = 0; ns < 4; ++ns) {
      int col = ns * 16 + ln;
      #pragma unroll
      for (int reg = 0; reg < 4; ++reg) {
        int row = mt * 64 + w * 16 + hq * 4 + reg;
        dst[(long)row * 64 + col] = f2b(acc[ns][reg]);
      }
    }
  } else {
    int b = mt >> 4;
    int tok = (mt * 64 + w * 16 + hq * 4) & 1023;
    #pragma unroll
    for (int ns = 0; ns < 4; ++ns) {
      int cv = (nt - 2) * 64 + ns * 16 + ln;
      union { short s[4]; short4v v; } o;
      #pragma unroll
      for (int reg = 0; reg < 4; ++reg) o.s[reg] = f2b(acc[ns][reg]);
      *(short4v*)(vtb + ((long)b * CC + cv) * NN + tok) = o.v;
    }
  }
}

// ---------------- Kernel B: r9 hot loop, mix in packed fp32 (v_pk_fma) ----
// grid 1024 (= 4 blocks/CU co-resident at 37376 B LDS):
// sp = bx&1, itile = (bx>>1)&63, b = bx>>7.
// Per 64-j tile: barA (drains K-gll) | stage masks + QK<-kbuf | barB |
// issue gll(K of jt+1 -> kbuf) | mix+PV.
// Mix pairs heads (l0,l1) into float2 lanes: weight/dot FMAs become packed
// v_pk_fma_f32 (2 FMA/slot) -> 24+8 scalar ops/zz -> 12+4 packed ops/zz.
// Per-lane IEEE math identical to r9 (same absmax).
#define IT 16
#define JT 64
#define SPLIT 2
#define JSPAN 512
#define NTL 8
#define ARP 260   // dwords per i-row of arec: arec[i][j*4+g]
#define MRP 196   // dwords per i-row of mrec: mrec[i][j*3+m]

__global__ __launch_bounds__(256, 3) void attn_kernel(
    const short* __restrict__ qb, const short* __restrict__ kb,
    const short* __restrict__ vtb, const float* __restrict__ masks,
    const float* __restrict__ mask_proj,
    float* __restrict__ pnum, float* __restrict__ pden)
{
  __shared__ float arec[IT * ARP];   // 16640 B
  __shared__ float mrec[IT * MRP];   // 12544 B
  __shared__ short kbuf[64 * 64];    //  8192 B   (37376 B total)

  const int t = threadIdx.x;
  const int sp = blockIdx.x & 1;
  const int itile = (blockIdx.x >> 1) & 63;
  const int b = blockIdx.x >> 7;
  const int i0 = itile * IT;

  const int w = t >> 6;          // wave id: g (QK) ; l-pair owner (mix+PV)
  const int lane = t & 63;
  const int ln = lane & 15;
  const int hq = lane >> 4;
  const int l0 = 2 * w, l1 = 2 * w + 1;

  // Q A-fragment (g = w), K-dim zero-padded 16->32 (hq>=2 lanes zero)
  short8 qf;
  {
    union { short s[8]; short8 v; } qq;
    #pragma unroll
    for (int z = 0; z < 8; ++z) qq.s[z] = 0;
    if (hq < 2)
      qq.v = *(const short8*)(qb + ((long)(b * NN + i0 + ln)) * GD + w * 16 + hq * 8);
    qf = qq.v;
  }
  // mix constants folded into exp2 domain; packed per head-pair {l0,l1}
  const float LOG2E = 1.44269504088896340736f;
  float2v ycP[3][4];
  #pragma unroll
  for (int m = 0; m < 3; ++m)
    #pragma unroll
    for (int g = 0; g < 4; ++g) {
      float2v p;
      p.x = mask_proj[m * 32 + g * 8 + l0] * LOG2E;
      p.y = mask_proj[m * 32 + g * 8 + l1] * LOG2E;
      ycP[m][g] = p;
    }

  const floatx4 zf = {0.f, 0.f, 0.f, 0.f};
  floatx4 pv0 = zf, pv1 = zf;
  float den0 = 0.f, den1 = 0.f;

  const short* kbase = kb + (long)b * NN * GD;
  const short* v0base = vtb + ((long)b * CC + l0 * 16 + ln) * NN;
  const short* v1base = vtb + ((long)b * CC + l1 * 16 + ln) * NN;

  // K-prefetch per-lane constants: wave w stages row-groups I = w*2, w*2+1
  const int klj = lane >> 3;              // row within 8-row group
  const int ke8 = (lane & 7) ^ klj;       // source d-octet (XOR pre-swizzle)

  // prologue: prefetch tile 0's K into kbuf (drained by first barA)
  #pragma unroll
  for (int ii = 0; ii < 2; ++ii) {
    const int I = w * 2 + ii;
    gll16(kbase + (long)(sp * JSPAN + I * 8 + klj) * GD + ke8 * 8,
          kbuf + I * 512, lane);
  }

  for (int jt = 0; jt < NTL; ++jt) {
    const int j0 = sp * JSPAN + jt * JT;
    __syncthreads();   // barA: prev mix readers done + K-gll drained (vmcnt 0)

    // ---- stage masks 16i x 64j x 3 (768 float4, coalesced) ----
    #pragma unroll
    for (int it2 = 0; it2 < 3; ++it2) {
      int f = t + it2 * 256;
      int ii = f / 48;
      int rem = f - ii * 48;
      *(float4*)(mrec + ii * MRP + rem * 4) =
        *(const float4*)(masks + (long)(i0 + ii) * (NN * 3) + (long)j0 * 3 + rem * 4);
    }
    // ---- QK: wave g = w, K from kbuf (XOR-chunk layout) ----
    #pragma unroll
    for (int jsub = 0; jsub < 4; ++jsub) {
      union { short s[8]; short8 v; } kk;
      #pragma unroll
      for (int z = 0; z < 8; ++z) kk.s[z] = 0;
      if (hq < 2) {
        const int jloc = jsub * 16 + ln;
        kk.v = *(const short8*)(kbuf + jloc * 64 + (((w * 2 + hq) ^ (jloc & 7)) << 3));
      }
      floatx4 at = __builtin_amdgcn_mfma_f32_16x16x32_bf16(qf, kk.v, zf, 0, 0, 0);
      float* ab = arec + (jsub * 16 + ln) * 4 + w;     // arec[i][j*4+g]
      #pragma unroll
      for (int reg = 0; reg < 4; ++reg)
        ab[(hq * 4 + reg) * ARP] = at[reg];
    }
    __syncthreads();   // barB: mrec + arec ready; all kbuf reads done

    // ---- issue NEXT tile's K prefetch (lands under the mix phase) ----
    {
      const int jn = sp * JSPAN + ((jt + 1) & (NTL - 1)) * JT;
      #pragma unroll
      for (int ii = 0; ii < 2; ++ii) {
        const int I = w * 2 + ii;
        gll16(kbase + (long)(jn + I * 8 + klj) * GD + ke8 * 8,
              kbuf + I * 512, lane);
      }
    }

    // ---- mix + exp2 + PV: thread = (i=ln, j-octet=hq), l = 2w, 2w+1 ----
    #pragma unroll
    for (int mf = 0; mf < 2; ++mf) {
      float mku[24];
      {
        const float* mb = mrec + ln * MRP + mf * 96 + hq * 24;
        #pragma unroll
        for (int q4 = 0; q4 < 6; ++q4)
          *(float4*)(mku + q4 * 4) = *(const float4*)(mb + q4 * 4);
      }
      short8 vf0 = *(const short8*)(v0base + j0 + mf * 32 + hq * 8);
      short8 vf1 = *(const short8*)(v1base + j0 + mf * 32 + hq * 8);
      const float* arA = arec + ln * ARP + (mf * 32 + hq * 8) * 4;
      union { unsigned u[4]; short8 v; } p0, p1;
      #pragma unroll
      for (int zp = 0; zp < 4; ++zp) {
        float eA[2], eB[2];
        #pragma unroll
        for (int zz = 0; zz < 2; ++zz) {
          int z = zp * 2 + zz;
          floatx4 a4 = *(const floatx4*)(arA + z * 4);
          float m0 = mku[z * 3], m1 = mku[z * 3 + 1], m2 = mku[z * 3 + 2];
          // packed head-pair weights: 12 v_pk ops (was 24 scalar)
          float2v w0 = m0 * ycP[0][0] + m1 * ycP[1][0] + m2 * ycP[2][0];
          float2v w1 = m0 * ycP[0][1] + m1 * ycP[1][1] + m2 * ycP[2][1];
          float2v w2 = m0 * ycP[0][2] + m1 * ycP[1][2] + m2 * ycP[2][2];
          float2v w3 = m0 * ycP[0][3] + m1 * ycP[1][3] + m2 * ycP[2][3];
          // packed dot: 4 v_pk ops (was 8 scalar)
          float2v s = a4[0] * w0 + a4[1] * w1 + a4[2] * w2 + a4[3] * w3;
          eA[zz] = EXP2(s.x);
          eB[zz] = EXP2(s.y);
        }
        den0 += eA[0] + eA[1];
        den1 += eB[0] + eB[1];
        p0.u[zp] = pk2(eA[0], eA[1]);
        p1.u[zp] = pk2(eB[0], eB[1]);
      }
      pv0 = __builtin_amdgcn_mfma_f32_16x16x32_bf16(p0.v, vf0, pv0, 0, 0, 0);
      pv1 = __builtin_amdgcn_mfma_f32_16x16x32_bf16(p1.v, vf1, pv1, 0, 0, 0);
    }
  }

  // ---- epilogue: partial numerators; den reduced over hq via shuffles ----
  #pragma unroll
  for (int reg = 0; reg < 4; ++reg) {
    long row = ((long)(sp * BB + b)) * NN + i0 + hq * 4 + reg;
    pnum[row * CC + l0 * 16 + ln] = pv0[reg];
    pnum[row * CC + l1 * 16 + ln] = pv1[reg];
  }
  // sum den over the 4 hq lanes (stride-16 within the wave)
  den0 += __shfl_xor(den0, 16, 64);
  den0 += __shfl_xor(den0, 32, 64);
  den1 += __shfl_xor(den1, 16, 64);
  den1 += __shfl_xor(den1, 32, 64);
  if (hq == 0) {
    long drow = ((long)(sp * BB + b)) * NN + i0 + ln;
    pden[drow * LL + l0] = den0;
    pden[drow * LL + l1] = den1;
  }
}

// ---------------- Kernel C: combine partials ----------------
__global__ __launch_bounds__(256) void reduce_kernel(
    const float* __restrict__ pnum, const float* __restrict__ pden,
    float* __restrict__ out)
{
  int e4 = blockIdx.x * 256 + threadIdx.x;   // float4 index
  int bi = e4 >> 5;                          // token 0..8191
  int l = (e4 & 31) >> 2;
  const float4* p4 = (const float4*)pnum;
  float4 n0 = p4[e4];
  float4 n1 = p4[e4 + (BB * NN * CC / 4)];
  float den = pden[(long)bi * LL + l] + pden[((long)BB * NN + bi) * LL + l];
  float inv = 1.0f / den;
  float4 o;
  o.x = (n0.x + n1.x) * inv;
  o.y = (n0.y + n1.y) * inv;
  o.z = (n0.z + n1.z) * inv;
  o.w = (n0.w + n1.w) * inv;
  ((float4*)out)[e4] = o;
}

extern "C" void kernel_launch(void* const* d_in, const int* in_sizes, int n_in,
                              void* d_out, int out_size, void* d_ws, size_t ws_size,
                              hipStream_t stream) {
  const float* x         = (const float*)d_in[0];
  const float* masks     = (const float*)d_in[1];
  const float* Wq        = (const float*)d_in[2];
  const float* Wk        = (const float*)d_in[3];
  const float* Wv        = (const float*)d_in[4];
  const float* mask_proj = (const float*)d_in[5];
  float* out = (float*)d_out;

  // ws bytes: qb 1M | kb 1M | vtb 2M | pnum 8M | pden 0.5M = 12.5 MB
  // (ws poison costs ~1 us/MB per iteration -- keep this small)
  char* wsB = (char*)d_ws;
  short* qb   = (short*)(wsB);
  short* kb   = (short*)(wsB + (1l << 20));
  short* vtb  = (short*)(wsB + (2l << 20));
  float* pnum = (float*)(wsB + (4l << 20));
  float* pden = (float*)(wsB + (12l << 20));

  proj_kernel<<<512, 256, 0, stream>>>(x, Wq, Wk, Wv, qb, kb, vtb);
  attn_kernel<<<BB * (NN / IT) * SPLIT, 256, 0, stream>>>(qb, kb, vtb, masks,
                                                          mask_proj, pnum, pden);
  reduce_kernel<<<(BB * NN * CC / 4) / 256, 256, 0, stream>>>(pnum, pden, out);
}

// Round 19
// 122.753 us; speedup vs baseline: 1.2178x; 1.0051x over previous
//
#include <hip/hip_runtime.h>

#define BB 8
#define NN 1024
#define CC 128
#define GG 4
#define LL 8
#define GD 64

typedef __attribute__((ext_vector_type(8))) short short8;
typedef __attribute__((ext_vector_type(4))) short short4v;
typedef __attribute__((ext_vector_type(4))) float floatx4;
typedef __attribute__((ext_vector_type(2))) float float2v;

__device__ __forceinline__ short f2b(float f) {
  union { float f; unsigned u; } c; c.f = f;
  unsigned u = c.u;
  return (short)((u + 0x7FFFu + ((u >> 16) & 1u)) >> 16);   // RNE fp32->bf16
}
__device__ __forceinline__ float b2f(short s) {
  union { unsigned u; float f; } c; c.u = ((unsigned)(unsigned short)s) << 16;
  return c.f;
}
__device__ __forceinline__ void split2(float v, short& hi, short& lo) {
  short h = f2b(v);
  hi = h;
  lo = f2b(v - b2f(h));
}

// packed fp32x2 -> bf16x2 (dword: low=a, high=b)
#if __has_builtin(__builtin_amdgcn_cvt_pk_bf16_f32)
__device__ __forceinline__ unsigned pk2(float a, float b) {
  auto r = __builtin_amdgcn_cvt_pk_bf16_f32(a, b);
  unsigned u; __builtin_memcpy(&u, &r, 4); return u;
}
#else
__device__ __forceinline__ unsigned pk2(float a, float b) {
  return (unsigned)(unsigned short)f2b(a) | ((unsigned)(unsigned short)f2b(b) << 16);
}
#endif

#if __has_builtin(__builtin_amdgcn_exp2f)
#define EXP2(x) __builtin_amdgcn_exp2f(x)
#else
#define EXP2(x) exp2f(x)
#endif

// async global->LDS, 16B per lane, dest = base + lane*16 (linear)
#if __has_builtin(__builtin_amdgcn_global_load_lds)
__device__ __forceinline__ void gll16(const void* g, void* l, int lane) {
  (void)lane;
  __builtin_amdgcn_global_load_lds(
      (const __attribute__((address_space(1))) unsigned int*)g,
      (__attribute__((address_space(3))) unsigned int*)l, 16, 0, 0);
}
#else
__device__ __forceinline__ void gll16(const void* g, void* l, int lane) {
  uint4 t = *(const uint4*)g;
  *(uint4*)((char*)l + lane * 16) = t;
}
#endif

// ---------------- Kernel A: projections, W hi/lo-split staged in LDS ------
#define BHP 136   // shorts per W row in LDS; 68 dwords, 68%32=4 -> 2-way free

__global__ __launch_bounds__(256) void proj_kernel(
    const float* __restrict__ x, const float* __restrict__ Wq,
    const float* __restrict__ Wk, const float* __restrict__ Wv,
    short* __restrict__ qb, short* __restrict__ kb, short* __restrict__ vtb)
{
  __shared__ short bh[64 * BHP];   // 17408 B
  __shared__ short bl[64 * BHP];   // 17408 B
  const int t = threadIdx.x;
  const int nt = blockIdx.x & 3;
  const int mt = blockIdx.x >> 2;
  const int w = t >> 6;
  const int lane = t & 63;
  const int ln = lane & 15;
  const int hq = lane >> 4;
  const int arow = mt * 64 + w * 16 + ln;

  const float* wbase = (nt == 0) ? Wq : (nt == 1) ? Wk : (Wv + (nt - 2) * 64 * 128);

  // stage + split W: thread -> row t>>2, cols (t&3)*32..+31
  {
    int r = t >> 2, c0 = (t & 3) * 32;
    const float* src = wbase + r * 128 + c0;
    #pragma unroll
    for (int z8 = 0; z8 < 4; ++z8) {
      float4 u0 = *(const float4*)(src + z8 * 8);
      float4 u1 = *(const float4*)(src + z8 * 8 + 4);
      float uv[8] = {u0.x,u0.y,u0.z,u0.w,u1.x,u1.y,u1.z,u1.w};
      union { short s[8]; short8 v; } H, L;
      #pragma unroll
      for (int z = 0; z < 8; ++z) split2(uv[z], H.s[z], L.s[z]);
      *(short8*)(bh + r * BHP + c0 + z8 * 8) = H.v;
      *(short8*)(bl + r * BHP + c0 + z8 * 8) = L.v;
    }
  }
  __syncthreads();

  const floatx4 zf = {0.f, 0.f, 0.f, 0.f};
  floatx4 acc[4] = {zf, zf, zf, zf};

  #pragma unroll
  for (int kc = 0; kc < 4; ++kc) {
    const float* xp = x + (long)arow * 128 + kc * 32 + hq * 8;
    float4 a0 = *(const float4*)xp;
    float4 a1 = *(const float4*)(xp + 4);
    union { short s[8]; short8 v; } Ah, Al;
    float av[8] = {a0.x,a0.y,a0.z,a0.w,a1.x,a1.y,a1.z,a1.w};
    #pragma unroll
    for (int z = 0; z < 8; ++z) split2(av[z], Ah.s[z], Al.s[z]);
    #pragma unroll
    for (int ns = 0; ns < 4; ++ns) {
      short8 Bh = *(const short8*)(bh + (ns * 16 + ln) * BHP + kc * 32 + hq * 8);
      short8 Bl = *(const short8*)(bl + (ns * 16 + ln) * BHP + kc * 32 + hq * 8);
      acc[ns] = __builtin_amdgcn_mfma_f32_16x16x32_bf16(Ah.v, Bh, acc[ns], 0,0,0);
      acc[ns] = __builtin_amdgcn_mfma_f32_16x16x32_bf16(Al.v, Bh, acc[ns], 0,0,0);
      acc[ns] = __builtin_amdgcn_mfma_f32_16x16x32_bf16(Ah.v, Bl, acc[ns], 0,0,0);
    }
  }

  if (nt < 2) {
    short* dst = (nt == 0) ? qb : kb;
    #pragma unroll
    for (int ns = 0; ns < 4; ++ns) {
      int col = ns * 16 + ln;
      #pragma unroll
      for (int reg = 0; reg < 4; ++reg) {
        int row = mt * 64 + w * 16 + hq * 4 + reg;
        dst[(long)row * 64 + col] = f2b(acc[ns][reg]);
      }
    }
  } else {
    int b = mt >> 4;
    int tok = (mt * 64 + w * 16 + hq * 4) & 1023;
    #pragma unroll
    for (int ns = 0; ns < 4; ++ns) {
      int cv = (nt - 2) * 64 + ns * 16 + ln;
      union { short s[4]; short4v v; } o;
      #pragma unroll
      for (int reg = 0; reg < 4; ++reg) o.s[reg] = f2b(acc[ns][reg]);
      *(short4v*)(vtb + ((long)b * CC + cv) * NN + tok) = o.v;
    }
  }
}

// ---------------- Kernel B: r18 hot loop, packed mix + packed den ---------
// grid 1024 (= 4 blocks/CU co-resident at 37376 B LDS):
// sp = bx&1, itile = (bx>>1)&63, b = bx>>7.
// Per 64-j tile: barA (drains K-gll) | stage masks + QK<-kbuf | barB |
// issue gll(K of jt+1 -> kbuf) | mix+PV.
// Mix pairs heads (l0,l1) in float2 lanes (v_pk_fma_f32): weights 12 pk ops,
// dot 4 pk ops per zz (r18, -6%). NEW: den accumulation also packed --
// denP += e0 + e1 with e_zz = {eA,eB}; per-component rounding order is
// IDENTICAL to scalar den0/den1 (same absmax), saves 16 VALU slots/tile.
#define IT 16
#define JT 64
#define SPLIT 2
#define JSPAN 512
#define NTL 8
#define ARP 260   // dwords per i-row of arec: arec[i][j*4+g]
#define MRP 196   // dwords per i-row of mrec: mrec[i][j*3+m]

__global__ __launch_bounds__(256, 3) void attn_kernel(
    const short* __restrict__ qb, const short* __restrict__ kb,
    const short* __restrict__ vtb, const float* __restrict__ masks,
    const float* __restrict__ mask_proj,
    float* __restrict__ pnum, float* __restrict__ pden)
{
  __shared__ float arec[IT * ARP];   // 16640 B
  __shared__ float mrec[IT * MRP];   // 12544 B
  __shared__ short kbuf[64 * 64];    //  8192 B   (37376 B total)

  const int t = threadIdx.x;
  const int sp = blockIdx.x & 1;
  const int itile = (blockIdx.x >> 1) & 63;
  const int b = blockIdx.x >> 7;
  const int i0 = itile * IT;

  const int w = t >> 6;          // wave id: g (QK) ; l-pair owner (mix+PV)
  const int lane = t & 63;
  const int ln = lane & 15;
  const int hq = lane >> 4;
  const int l0 = 2 * w, l1 = 2 * w + 1;

  // Q A-fragment (g = w), K-dim zero-padded 16->32 (hq>=2 lanes zero)
  short8 qf;
  {
    union { short s[8]; short8 v; } qq;
    #pragma unroll
    for (int z = 0; z < 8; ++z) qq.s[z] = 0;
    if (hq < 2)
      qq.v = *(const short8*)(qb + ((long)(b * NN + i0 + ln)) * GD + w * 16 + hq * 8);
    qf = qq.v;
  }
  // mix constants folded into exp2 domain; packed per head-pair {l0,l1}
  const float LOG2E = 1.44269504088896340736f;
  float2v ycP[3][4];
  #pragma unroll
  for (int m = 0; m < 3; ++m)
    #pragma unroll
    for (int g = 0; g < 4; ++g) {
      float2v p;
      p.x = mask_proj[m * 32 + g * 8 + l0] * LOG2E;
      p.y = mask_proj[m * 32 + g * 8 + l1] * LOG2E;
      ycP[m][g] = p;
    }

  const floatx4 zf = {0.f, 0.f, 0.f, 0.f};
  floatx4 pv0 = zf, pv1 = zf;
  float2v denP = {0.f, 0.f};

  const short* kbase = kb + (long)b * NN * GD;
  const short* v0base = vtb + ((long)b * CC + l0 * 16 + ln) * NN;
  const short* v1base = vtb + ((long)b * CC + l1 * 16 + ln) * NN;

  // K-prefetch per-lane constants: wave w stages row-groups I = w*2, w*2+1
  const int klj = lane >> 3;              // row within 8-row group
  const int ke8 = (lane & 7) ^ klj;       // source d-octet (XOR pre-swizzle)

  // prologue: prefetch tile 0's K into kbuf (drained by first barA)
  #pragma unroll
  for (int ii = 0; ii < 2; ++ii) {
    const int I = w * 2 + ii;
    gll16(kbase + (long)(sp * JSPAN + I * 8 + klj) * GD + ke8 * 8,
          kbuf + I * 512, lane);
  }

  for (int jt = 0; jt < NTL; ++jt) {
    const int j0 = sp * JSPAN + jt * JT;
    __syncthreads();   // barA: prev mix readers done + K-gll drained (vmcnt 0)

    // ---- stage masks 16i x 64j x 3 (768 float4, coalesced) ----
    #pragma unroll
    for (int it2 = 0; it2 < 3; ++it2) {
      int f = t + it2 * 256;
      int ii = f / 48;
      int rem = f - ii * 48;
      *(float4*)(mrec + ii * MRP + rem * 4) =
        *(const float4*)(masks + (long)(i0 + ii) * (NN * 3) + (long)j0 * 3 + rem * 4);
    }
    // ---- QK: wave g = w, K from kbuf (XOR-chunk layout) ----
    #pragma unroll
    for (int jsub = 0; jsub < 4; ++jsub) {
      union { short s[8]; short8 v; } kk;
      #pragma unroll
      for (int z = 0; z < 8; ++z) kk.s[z] = 0;
      if (hq < 2) {
        const int jloc = jsub * 16 + ln;
        kk.v = *(const short8*)(kbuf + jloc * 64 + (((w * 2 + hq) ^ (jloc & 7)) << 3));
      }
      floatx4 at = __builtin_amdgcn_mfma_f32_16x16x32_bf16(qf, kk.v, zf, 0, 0, 0);
      float* ab = arec + (jsub * 16 + ln) * 4 + w;     // arec[i][j*4+g]
      #pragma unroll
      for (int reg = 0; reg < 4; ++reg)
        ab[(hq * 4 + reg) * ARP] = at[reg];
    }
    __syncthreads();   // barB: mrec + arec ready; all kbuf reads done

    // ---- issue NEXT tile's K prefetch (lands under the mix phase) ----
    {
      const int jn = sp * JSPAN + ((jt + 1) & (NTL - 1)) * JT;
      #pragma unroll
      for (int ii = 0; ii < 2; ++ii) {
        const int I = w * 2 + ii;
        gll16(kbase + (long)(jn + I * 8 + klj) * GD + ke8 * 8,
              kbuf + I * 512, lane);
      }
    }

    // ---- mix + exp2 + PV: thread = (i=ln, j-octet=hq), l = 2w, 2w+1 ----
    #pragma unroll
    for (int mf = 0; mf < 2; ++mf) {
      float mku[24];
      {
        const float* mb = mrec + ln * MRP + mf * 96 + hq * 24;
        #pragma unroll
        for (int q4 = 0; q4 < 6; ++q4)
          *(float4*)(mku + q4 * 4) = *(const float4*)(mb + q4 * 4);
      }
      short8 vf0 = *(const short8*)(v0base + j0 + mf * 32 + hq * 8);
      short8 vf1 = *(const short8*)(v1base + j0 + mf * 32 + hq * 8);
      const float* arA = arec + ln * ARP + (mf * 32 + hq * 8) * 4;
      union { unsigned u[4]; short8 v; } p0, p1;
      #pragma unroll
      for (int zp = 0; zp < 4; ++zp) {
        float2v e[2];
        #pragma unroll
        for (int zz = 0; zz < 2; ++zz) {
          int z = zp * 2 + zz;
          floatx4 a4 = *(const floatx4*)(arA + z * 4);
          float m0 = mku[z * 3], m1 = mku[z * 3 + 1], m2 = mku[z * 3 + 2];
          // packed head-pair weights: 12 v_pk ops (was 24 scalar)
          float2v w0 = m0 * ycP[0][0] + m1 * ycP[1][0] + m2 * ycP[2][0];
          float2v w1 = m0 * ycP[0][1] + m1 * ycP[1][1] + m2 * ycP[2][1];
          float2v w2 = m0 * ycP[0][2] + m1 * ycP[1][2] + m2 * ycP[2][2];
          float2v w3 = m0 * ycP[0][3] + m1 * ycP[1][3] + m2 * ycP[2][3];
          // packed dot: 4 v_pk ops (was 8 scalar)
          float2v s = a4[0] * w0 + a4[1] * w1 + a4[2] * w2 + a4[3] * w3;
          float2v ev;
          ev.x = EXP2(s.x);
          ev.y = EXP2(s.y);
          e[zz] = ev;
        }
        // packed den accumulation: per-component order identical to scalar
        denP += e[0] + e[1];
        p0.u[zp] = pk2(e[0].x, e[1].x);
        p1.u[zp] = pk2(e[0].y, e[1].y);
      }
      pv0 = __builtin_amdgcn_mfma_f32_16x16x32_bf16(p0.v, vf0, pv0, 0, 0, 0);
      pv1 = __builtin_amdgcn_mfma_f32_16x16x32_bf16(p1.v, vf1, pv1, 0, 0, 0);
    }
  }

  // ---- epilogue: partial numerators; den reduced over hq via shuffles ----
  #pragma unroll
  for (int reg = 0; reg < 4; ++reg) {
    long row = ((long)(sp * BB + b)) * NN + i0 + hq * 4 + reg;
    pnum[row * CC + l0 * 16 + ln] = pv0[reg];
    pnum[row * CC + l1 * 16 + ln] = pv1[reg];
  }
  // sum den over the 4 hq lanes (stride-16 within the wave)
  float den0 = denP.x, den1 = denP.y;
  den0 += __shfl_xor(den0, 16, 64);
  den0 += __shfl_xor(den0, 32, 64);
  den1 += __shfl_xor(den1, 16, 64);
  den1 += __shfl_xor(den1, 32, 64);
  if (hq == 0) {
    long drow = ((long)(sp * BB + b)) * NN + i0 + ln;
    pden[drow * LL + l0] = den0;
    pden[drow * LL + l1] = den1;
  }
}

// ---------------- Kernel C: combine partials ----------------
__global__ __launch_bounds__(256) void reduce_kernel(
    const float* __restrict__ pnum, const float* __restrict__ pden,
    float* __restrict__ out)
{
  int e4 = blockIdx.x * 256 + threadIdx.x;   // float4 index
  int bi = e4 >> 5;                          // token 0..8191
  int l = (e4 & 31) >> 2;
  const float4* p4 = (const float4*)pnum;
  float4 n0 = p4[e4];
  float4 n1 = p4[e4 + (BB * NN * CC / 4)];
  float den = pden[(long)bi * LL + l] + pden[((long)BB * NN + bi) * LL + l];
  float inv = 1.0f / den;
  float4 o;
  o.x = (n0.x + n1.x) * inv;
  o.y = (n0.y + n1.y) * inv;
  o.z = (n0.z + n1.z) * inv;
  o.w = (n0.w + n1.w) * inv;
  ((float4*)out)[e4] = o;
}

extern "C" void kernel_launch(void* const* d_in, const int* in_sizes, int n_in,
                              void* d_out, int out_size, void* d_ws, size_t ws_size,
                              hipStream_t stream) {
  const float* x         = (const float*)d_in[0];
  const float* masks     = (const float*)d_in[1];
  const float* Wq        = (const float*)d_in[2];
  const float* Wk        = (const float*)d_in[3];
  const float* Wv        = (const float*)d_in[4];
  const float* mask_proj = (const float*)d_in[5];
  float* out = (float*)d_out;

  // ws bytes: qb 1M | kb 1M | vtb 2M | pnum 8M | pden 0.5M = 12.5 MB
  // (ws poison costs ~1 us/MB per iteration -- keep this small)
  char* wsB = (char*)d_ws;
  short* qb   = (short*)(wsB);
  short* kb   = (short*)(wsB + (1l << 20));
  short* vtb  = (short*)(wsB + (2l << 20));
  float* pnum = (float*)(wsB + (4l << 20));
  float* pden = (float*)(wsB + (12l << 20));

  proj_kernel<<<512, 256, 0, stream>>>(x, Wq, Wk, Wv, qb, kb, vtb);
  attn_kernel<<<BB * (NN / IT) * SPLIT, 256, 0, stream>>>(qb, kb, vtb, masks,
                                                          mask_proj, pnum, pden);
  reduce_kernel<<<(BB * NN * CC / 4) / 256, 256, 0, stream>>>(pnum, pden, out);
}